// Round 11
// baseline (404.596 us; speedup 1.0000x reference)
//
#include <hip/hip_runtime.h>
#include <math.h>

#define NN    10000
#define SSS   4
#define LL    8
#define HH    128
#define NSEQ  40000
#define SUBN  100
#define ORIGF 64
#define TA    512

// ---- fallback path (R10): heterogeneous tiling 768 fat + 196 thin ----
#define FATB  768
#define FATQ  (FATB * 48)
#define TAILB ((NSEQ - FATQ) / 16)
#define GRID  (FATB + TAILB)

// ---- big-ws path: NSS=5, MA=80, 500 blocks = EXACTLY 2 rounds on 256 CUs ----
#define MA5   80
#define GRID5 (NSEQ / MA5)    // 500 exact

typedef unsigned short u16;
typedef short bf16x8 __attribute__((ext_vector_type(8)));
typedef float f32x4 __attribute__((ext_vector_type(4)));

#define L2E 1.4426950408889634f

// ---- R10 LDS layout (fallback kernel) ----
#define WL_OFF    0
#define BWRZ_OFF  6144
#define BWIN_OFF  7168
#define BWHN_OFF  7680     // b_ss f32[64] overlay after bias regs read
#define BMRZ_OFF  8192
#define BMIN_OFF  9216
#define BMHN_OFF  9728
#define HB_OFF    10240
#define HB_STR    128
#define HBBUF     2048
#define HB_SSTR   4096
#define XB_OFF    34816
#define XB_STR    128
#define XB_SSTR   16384
#define SWF_OFF   133120
#define SUF_OFF   134656
#define SCNT_OFF  136192
#define SANY_OFF  136384
#define WSSA_ROWS 24
#define WSSA_OFF  WL_OFF
#define WSSB_OFF  136448
#define RED_OFF   136448
#define LDS_TOTAL 163072

// ---- k_rum5 LDS layout (XB moved to global ws -> 5 streams fit) ----
#define Q_HB_OFF   10240   // u16[5][2][16*128]
#define Q_SWF_OFF  51200   // int[80*8]
#define Q_SUF_OFF  53760   // int[80*8]
#define Q_SCNT_OFF 56320   // int[80]
#define Q_SANY_OFF 56640   // int
#define Q_WSS_OFF  56704   // f32 wssT[128][64], 256 B rows
#define Q_RED_OFF  56704   // reduction overlay (W_ss dead by then)
#define Q_LDS      89472   // 87.4 KiB

// ws: ws[0..3] accum; byte 64: bf16 weights (whhw|whh|wih), bf16 hfeat,
// then (big-ws only) bf16 y_walk[NSEQ][LL][HH]
#define WB_BYTE_OFF 64
#define W_HHW_N 49152
#define W_HH_N  49152
#define W_IH_N  98304
#define W_TOTAL (W_HHW_N + W_HH_N + W_IH_N)
#define WS_NEED  ((size_t)WB_BYTE_OFF + (size_t)W_TOTAL * 2 + (size_t)NN * HH * 2)
#define WS_NEED2 (WS_NEED + (size_t)NSEQ * LL * HH * 2)   // ~84.9 MB

__device__ __forceinline__ float bf2f(u16 u) {
  return __uint_as_float(((unsigned)u) << 16);
}
__device__ __forceinline__ u16 f2bf(float f) {
  unsigned u = __float_as_uint(f);
  u += 0x7fffu + ((u >> 16) & 1u);   // RNE
  return (u16)(u >> 16);
}
__device__ __forceinline__ bf16x8 pack8(float4 v0, float4 v1) {
  bf16x8 r;
  r[0] = (short)f2bf(v0.x); r[1] = (short)f2bf(v0.y);
  r[2] = (short)f2bf(v0.z); r[3] = (short)f2bf(v0.w);
  r[4] = (short)f2bf(v1.x); r[5] = (short)f2bf(v1.y);
  r[6] = (short)f2bf(v1.z); r[7] = (short)f2bf(v1.w);
  return r;
}
__device__ __forceinline__ float sig2_(float xs) {
  return __builtin_amdgcn_rcpf(1.f + __builtin_amdgcn_exp2f(-xs));
}
__device__ __forceinline__ float tanh2_(float xs) {
  return 1.f - 2.f * __builtin_amdgcn_rcpf(__builtin_amdgcn_exp2f(xs) + 1.f);
}
__device__ __forceinline__ float softplusf_(float x) {
  return fmaxf(x, 0.f) + log1pf(__expf(-fabsf(x)));
}

__global__ void k_zero(float* ws) {
  if (threadIdx.x < 4) ws[threadIdx.x] = 0.f;
}

__global__ void k_prep(const float* __restrict__ whhw, const float* __restrict__ whh,
                       const float* __restrict__ wih, float* __restrict__ ws) {
  const int i = blockIdx.x * 256 + threadIdx.x;
  u16* wb = (u16*)((char*)ws + WB_BYTE_OFF);
  if (i < W_HHW_N) {
    const int row = i >> 7;
    wb[i] = f2bf(whhw[i] * ((row < 256) ? L2E : 2.f * L2E));
  } else if (i < W_HHW_N + W_HH_N) {
    const int j = i - W_HHW_N, row = j >> 7;
    wb[i] = f2bf(whh[j] * ((row < 256) ? L2E : 2.f * L2E));
  } else {
    const int j = i - W_HHW_N - W_HH_N, row = j >> 8;
    wb[i] = f2bf(wih[j] * ((row < 256) ? L2E : 2.f * L2E));
  }
}

__global__ void k_prep_h(const float* __restrict__ h, float* __restrict__ ws) {
  const int i = blockIdx.x * 256 + threadIdx.x;
  u16* hb16 = (u16*)((char*)ws + WB_BYTE_OFF) + W_TOTAL;
  hb16[i] = f2bf(h[i]);
}

// ======================= big-ws kernel: NSS=5, y_walk in global ws =========
// LDS 87KB (XB -> global). +8 persistent regs only (hreg[5] vs [3]).
// SS inner loop stays `#pragma unroll 1` (R9: full unroll -> spills).
__global__ __launch_bounds__(TA, 2) void k_rum5(
    const float* __restrict__ y0,
    const float* __restrict__ WihW,  const float* __restrict__ bihW,
    const float* __restrict__ bhhW,
    const float* __restrict__ bih,   const float* __restrict__ bhh,
    const float* __restrict__ W_ss,  const float* __restrict__ b_ss,
    const int* __restrict__ walks,   const int* __restrict__ idxs,
    float* __restrict__ out, float* __restrict__ ws)
{
  constexpr int NSS = 5, MAS = MA5;
  extern __shared__ char sm[];
  u16*   WLb  = (u16*)(sm + WL_OFF);
  float* bwrz = (float*)(sm + BWRZ_OFF);
  float* bwin = (float*)(sm + BWIN_OFF);
  float* bwhn = (float*)(sm + BWHN_OFF);
  float* bmrz = (float*)(sm + BMRZ_OFF);
  float* bmin = (float*)(sm + BMIN_OFF);
  float* bmhn = (float*)(sm + BMHN_OFF);
  u16*   hb   = (u16*)(sm + Q_HB_OFF);
  int*   swf  = (int*)(sm + Q_SWF_OFF);
  int*   suf  = (int*)(sm + Q_SUF_OFF);
  int*   scnt = (int*)(sm + Q_SCNT_OFF);
  int*   sany = (int*)(sm + Q_SANY_OFF);

  const u16* wb     = (const u16*)((const char*)ws + WB_BYTE_OFF);
  const u16* whhw_b = wb;
  const u16* whh_b  = wb + W_HHW_N;
  const u16* wih_b  = wb + W_HHW_N + W_HH_N;
  const u16* hf16   = wb + W_TOTAL;
  u16*       ywg    = (u16*)((char*)ws + WB_BYTE_OFF) + W_TOTAL + NN * HH;

  const int tid = threadIdx.x;
  const int lane = tid & 63, c = lane & 15, qd = lane >> 4;
  const int wv = tid >> 6;
  const int i0 = wv * 16 + c;
  const int q0 = blockIdx.x * MAS;

  // ---- phase 0 (500*80 = 40000 exact: no guards) ----
  if (tid < MAS) {
    const int m = tid;
    scnt[m] = 0;
    const int q = q0 + m;
    int w[LL];
    #pragma unroll
    for (int l = 0; l < LL; ++l) w[l] = walks[q * LL + l];
    #pragma unroll
    for (int l = 0; l < LL; ++l) {
      int u = l;
      #pragma unroll
      for (int l2 = LL - 1; l2 >= 0; --l2) if (w[l2] == w[l]) u = l2;
      swf[m * LL + (LL - 1 - l)] = w[l];
      suf[m * LL + (LL - 1 - l)] = u;
    }
  }
  if (tid == 0) *sany = 0;
  for (int idx = tid; idx < 3072; idx += TA)
    WLb[idx] = f2bf(WihW[idx] * ((idx < 2048) ? L2E : 2.f * L2E));
  if (tid < 256) {
    bwrz[tid] = (bihW[tid] + bhhW[tid]) * L2E;
    bmrz[tid] = (bih[tid] + bhh[tid]) * L2E;
  }
  if (tid < 128) {
    bwin[tid] = 2.f * L2E * bihW[256 + tid]; bwhn[tid] = 2.f * L2E * bhhW[256 + tid];
    bmin[tid] = 2.f * L2E * bih[256 + tid];  bmhn[tid] = 2.f * L2E * bhh[256 + tid];
  }
  __syncthreads();

  for (int p = tid; p < MAS * SUBN; p += TA) {
    const int m = p / SUBN, i = p % SUBN;
    if (idxs[i] == (q0 + m) % NN) { atomicAdd(&scnt[m], 1); *sany = 1; }
  }

  const float bw1 = bwrz[i0], bw2 = bwrz[HH + i0], bw3 = bwin[i0], bw4 = bwhn[i0];
  const float bm1 = bmrz[i0], bm2 = bmrz[HH + i0], bm3 = bmin[i0], bm4 = bmhn[i0];

  float hreg[NSS][4];
  #pragma unroll
  for (int s = 0; s < NSS; ++s)
    #pragma unroll
    for (int r2 = 0; r2 < 4; ++r2) hreg[s][r2] = 0.f;

  // ---- walk GRU: 5 streams, y_walk -> GLOBAL ws (32B-chunk coalesced) ----
  {
    bf16x8 BA[3][4];
    #pragma unroll
    for (int tl = 0; tl < 3; ++tl) {
      const int row = (tl * 8 + wv) * 16 + c;
      #pragma unroll
      for (int k = 0; k < 4; ++k)
        BA[tl][k] = *(const bf16x8*)(whhw_b + row * HH + k * 32 + qd * 8);
    }
    #pragma unroll 1
    for (int t = 0; t < LL; ++t) {
      #pragma unroll
      for (int s = 0; s < NSS; ++s) {
        f32x4 D[3];
        #pragma unroll
        for (int tl = 0; tl < 3; ++tl) D[tl] = (f32x4){0.f, 0.f, 0.f, 0.f};
        if (t > 0) {
          const u16* hbc = hb + s * HB_SSTR + (t & 1) * HBBUF;
          bf16x8 a[4];
          #pragma unroll
          for (int k = 0; k < 4; ++k)
            a[k] = *(const bf16x8*)(hbc + c * HB_STR + (((4 * k + qd) ^ c) << 3));
          #pragma unroll
          for (int tl = 0; tl < 3; ++tl) {
            f32x4 d = D[tl];
            #pragma unroll
            for (int k = 0; k < 4; ++k)
              d = __builtin_amdgcn_mfma_f32_16x16x32_bf16(a[k], BA[tl][k], d, 0, 0, 0);
            D[tl] = d;
          }
        }
        u16* hbn = hb + s * HB_SSTR + ((t + 1) & 1) * HBBUF;
        #pragma unroll
        for (int reg = 0; reg < 4; ++reg) {
          const int ml = qd * 4 + reg;
          const int u = suf[(s * 16 + ml) * LL + t];
          const float r = sig2_(bf2f(WLb[i0 * LL + u]) + D[0][reg] + bw1);
          const float z = sig2_(bf2f(WLb[(HH + i0) * LL + u]) + D[1][reg] + bw2);
          const float n = tanh2_(bf2f(WLb[(2 * HH + i0) * LL + u]) + bw3
                                 + r * (D[2][reg] + bw4));
          const float hn = n + z * (hreg[s][reg] - n);
          hreg[s][reg] = hn;
          const u16 hv = f2bf(hn);
          hbn[ml * HB_STR + (((i0 >> 3) ^ ml) << 3) + (i0 & 7)] = hv;
          ywg[((size_t)(q0 + s * 16 + ml) * LL + t) * HH + i0] = hv;
        }
      }
      __syncthreads();
    }
  }

  const bool anyf = (*sany != 0);

  // ---- stage W_ss^T (f32) + b_ss into LDS (anyf blocks only) ----
  if (anyf) {
    if (tid < ORIGF) ((float*)(sm + BWHN_OFF))[tid] = b_ss[tid];
    for (int idx = tid; idx < HH * ORIGF; idx += TA) {
      const int kc = idx & 127, o = idx >> 7;
      ((float*)(sm + Q_WSS_OFF + kc * 256))[o] = W_ss[o * HH + kc];
    }
  }

  // ---- main-phase weight fragments ----
  bf16x8 BW[3][8], BC[3][4];
  #pragma unroll
  for (int tl = 0; tl < 3; ++tl) {
    const int row = (tl * 8 + wv) * 16 + c;
    #pragma unroll
    for (int kk = 0; kk < 8; ++kk)
      BW[tl][kk] = *(const bf16x8*)(wih_b + row * 256 + kk * 32 + qd * 8);
    #pragma unroll
    for (int k = 0; k < 4; ++k)
      BC[tl][k] = *(const bf16x8*)(whh_b + row * HH + k * 32 + qd * 8);
  }

  float pAcc = 0.f, pBcc = 0.f, pScc = 0.f;

  // ---- main GRU: 5 streams; ay from global y_walk (same-block-written ->
  // L2/L3 hit, issued at section top) ----
  #pragma unroll 1
  for (int t = 0; t < LL; ++t) {
    #pragma unroll
    for (int s = 0; s < NSS; ++s) {
      const int node = swf[(s * 16 + c) * LL + t];
      const u16* hp = hf16 + (size_t)node * HH + qd * 8;
      bf16x8 ah[4];
      #pragma unroll
      for (int k = 0; k < 4; ++k) ah[k] = *(const bf16x8*)(hp + k * 32);
      const u16* yp = ywg + ((size_t)(q0 + s * 16 + c) * LL + t) * HH + qd * 8;
      bf16x8 ay[4];
      #pragma unroll
      for (int k = 0; k < 4; ++k) ay[k] = *(const bf16x8*)(yp + k * 32);
      const u16* hbc = hb + s * HB_SSTR + (t & 1) * HBBUF;
      bf16x8 a[4];
      #pragma unroll
      for (int k = 0; k < 4; ++k)
        a[k] = *(const bf16x8*)(hbc + c * HB_STR + (((4 * k + qd) ^ c) << 3));

      f32x4 Drz[2], Dnr, Dni;
      #pragma unroll
      for (int tl = 0; tl < 2; ++tl) {      // r,z fused
        f32x4 d = {0.f, 0.f, 0.f, 0.f};
        #pragma unroll
        for (int k = 0; k < 4; ++k)
          d = __builtin_amdgcn_mfma_f32_16x16x32_bf16(a[k], BC[tl][k], d, 0, 0, 0);
        #pragma unroll
        for (int k = 0; k < 4; ++k)
          d = __builtin_amdgcn_mfma_f32_16x16x32_bf16(ah[k], BW[tl][k], d, 0, 0, 0);
        #pragma unroll
        for (int k = 0; k < 4; ++k)
          d = __builtin_amdgcn_mfma_f32_16x16x32_bf16(ay[k], BW[tl][4 + k], d, 0, 0, 0);
        Drz[tl] = d;
      }
      {                                      // n split (r scales rec only)
        f32x4 dr = {0.f, 0.f, 0.f, 0.f}, di = {0.f, 0.f, 0.f, 0.f};
        #pragma unroll
        for (int k = 0; k < 4; ++k)
          dr = __builtin_amdgcn_mfma_f32_16x16x32_bf16(a[k], BC[2][k], dr, 0, 0, 0);
        #pragma unroll
        for (int k = 0; k < 4; ++k)
          di = __builtin_amdgcn_mfma_f32_16x16x32_bf16(ah[k], BW[2][k], di, 0, 0, 0);
        #pragma unroll
        for (int k = 0; k < 4; ++k)
          di = __builtin_amdgcn_mfma_f32_16x16x32_bf16(ay[k], BW[2][4 + k], di, 0, 0, 0);
        Dnr = dr; Dni = di;
      }
      u16* hbn = hb + s * HB_SSTR + ((t + 1) & 1) * HBBUF;
      #pragma unroll
      for (int reg = 0; reg < 4; ++reg) {
        const int ml = qd * 4 + reg;
        const float r = sig2_(Drz[0][reg] + bm1);
        const float z = sig2_(Drz[1][reg] + bm2);
        const float n = tanh2_(Dni[reg] + bm3 + r * (Dnr[reg] + bm4));
        const float hn = n + z * (hreg[s][reg] - n);
        hreg[s][reg] = hn;
        hbn[ml * HB_STR + (((i0 >> 3) ^ ml) << 3) + (i0 & 7)] = f2bf(hn);
      }
    }

    if (t < LL - 1 && anyf) {
      __syncthreads();
      const float* bssl = (const float*)(sm + BWHN_OFF);
      for (int idx = tid; idx < MAS * ORIGF; idx += TA) {
        const int m = idx >> 6, o = idx & 63;
        const int cnt = scnt[m];
        if (cnt > 0) {
          const int ml = m & 15;
          const u16* hrow = hb + (m >> 4) * HB_SSTR + ((t + 1) & 1) * HBBUF
                          + ml * HB_STR;
          const float fc = (float)cnt;
          const float yt = y0[(size_t)swf[m * LL + t + 1] * ORIGF + o];
          float a0 = bssl[o], a1 = 0.f, a2 = 0.f, a3 = 0.f;
          #pragma unroll 1
          for (int kc8 = 0; kc8 < 16; ++kc8) {
            const bf16x8 xv = *(const bf16x8*)(hrow + ((kc8 ^ ml) << 3));
            const char* wbase = sm + Q_WSS_OFF + kc8 * 2048;
            a0 = fmaf(((const float*)(wbase))[o],        bf2f((u16)xv[0]), a0);
            a1 = fmaf(((const float*)(wbase + 256))[o],  bf2f((u16)xv[1]), a1);
            a2 = fmaf(((const float*)(wbase + 512))[o],  bf2f((u16)xv[2]), a2);
            a3 = fmaf(((const float*)(wbase + 768))[o],  bf2f((u16)xv[3]), a3);
            a0 = fmaf(((const float*)(wbase + 1024))[o], bf2f((u16)xv[4]), a0);
            a1 = fmaf(((const float*)(wbase + 1280))[o], bf2f((u16)xv[5]), a1);
            a2 = fmaf(((const float*)(wbase + 1536))[o], bf2f((u16)xv[6]), a2);
            a3 = fmaf(((const float*)(wbase + 1792))[o], bf2f((u16)xv[7]), a3);
          }
          const float acc = (a0 + a1) + (a2 + a3);
          const float sp = softplusf_(-acc);
          pAcc += fc * yt * sp;
          pBcc += fc * (1.f - yt) * (sp + acc);
          pScc += fc * yt;
        }
      }
    }
    __syncthreads();
  }

  // ---- epilogue ----
  #pragma unroll
  for (int s = 0; s < NSS; ++s)
    #pragma unroll
    for (int reg = 0; reg < 4; ++reg)
      out[(size_t)(q0 + s * 16 + qd * 4 + reg) * HH + i0] = hreg[s][reg];

  if (anyf) {
    float* red = (float*)(sm + Q_RED_OFF);
    red[tid] = pAcc; red[TA + tid] = pBcc; red[2 * TA + tid] = pScc;
    __syncthreads();
    if (wv == 0) {
      float a = 0.f, b = 0.f, s = 0.f;
      for (int k2 = lane; k2 < TA; k2 += 64) {
        a += red[k2]; b += red[TA + k2]; s += red[2 * TA + k2];
      }
      #pragma unroll
      for (int off = 32; off > 0; off >>= 1) {
        a += __shfl_down(a, off); b += __shfl_down(b, off); s += __shfl_down(s, off);
      }
      if (lane == 0) {
        atomicAdd(&ws[1], a); atomicAdd(&ws[2], b); atomicAdd(&ws[3], s);
      }
    }
  }
}

// ======================= fallback kernel: R10 verbatim =====================
template<bool BF, int NSS>
__device__ __forceinline__ void rum_body(
    const int q0,
    const float* __restrict__ hfeat, const float* __restrict__ y0,
    const float* __restrict__ WihW,  const float* __restrict__ bihW,
    const float* __restrict__ bhhW,
    const float* __restrict__ bih,   const float* __restrict__ bhh,
    const float* __restrict__ W_ss,  const float* __restrict__ b_ss,
    const int* __restrict__ walks,   const int* __restrict__ idxs,
    float* __restrict__ out, float* __restrict__ ws)
{
  constexpr int MAS = 16 * NSS;
  extern __shared__ char sm[];
  u16*   WLb  = (u16*)(sm + WL_OFF);
  float* bwrz = (float*)(sm + BWRZ_OFF);
  float* bwin = (float*)(sm + BWIN_OFF);
  float* bwhn = (float*)(sm + BWHN_OFF);
  float* bmrz = (float*)(sm + BMRZ_OFF);
  float* bmin = (float*)(sm + BMIN_OFF);
  float* bmhn = (float*)(sm + BMHN_OFF);
  u16*   hb   = (u16*)(sm + HB_OFF);
  u16*   xb   = (u16*)(sm + XB_OFF);
  int*   swf  = (int*)(sm + SWF_OFF);
  int*   suf  = (int*)(sm + SUF_OFF);
  int*   scnt = (int*)(sm + SCNT_OFF);
  int*   sany = (int*)(sm + SANY_OFF);

  const u16* wb     = (const u16*)((const char*)ws + WB_BYTE_OFF);
  const u16* whhw_b = wb;
  const u16* whh_b  = wb + W_HHW_N;
  const u16* wih_b  = wb + W_HHW_N + W_HH_N;
  const u16* hf16   = wb + W_TOTAL;

  const int tid = threadIdx.x;
  const int lane = tid & 63, c = lane & 15, qd = lane >> 4;
  const int wv = tid >> 6;
  const int i0 = wv * 16 + c;

  if (tid < MAS) {
    const int m = tid;
    scnt[m] = 0;
    const int q = q0 + m;
    int w[LL];
    #pragma unroll
    for (int l = 0; l < LL; ++l) w[l] = walks[q * LL + l];
    #pragma unroll
    for (int l = 0; l < LL; ++l) {
      int u = l;
      #pragma unroll
      for (int l2 = LL - 1; l2 >= 0; --l2) if (w[l2] == w[l]) u = l2;
      swf[m * LL + (LL - 1 - l)] = w[l];
      suf[m * LL + (LL - 1 - l)] = u;
    }
  }
  if (tid == 0) *sany = 0;
  for (int idx = tid; idx < 3072; idx += TA)
    WLb[idx] = f2bf(WihW[idx] * ((idx < 2048) ? L2E : 2.f * L2E));
  if (tid < 256) {
    bwrz[tid] = (bihW[tid] + bhhW[tid]) * L2E;
    bmrz[tid] = (bih[tid] + bhh[tid]) * L2E;
  }
  if (tid < 128) {
    bwin[tid] = 2.f * L2E * bihW[256 + tid]; bwhn[tid] = 2.f * L2E * bhhW[256 + tid];
    bmin[tid] = 2.f * L2E * bih[256 + tid];  bmhn[tid] = 2.f * L2E * bhh[256 + tid];
  }
  __syncthreads();

  for (int p = tid; p < MAS * SUBN; p += TA) {
    const int m = p / SUBN, i = p % SUBN;
    if (idxs[i] == (q0 + m) % NN) { atomicAdd(&scnt[m], 1); *sany = 1; }
  }

  const float bw1 = bwrz[i0], bw2 = bwrz[HH + i0], bw3 = bwin[i0], bw4 = bwhn[i0];
  const float bm1 = bmrz[i0], bm2 = bmrz[HH + i0], bm3 = bmin[i0], bm4 = bmhn[i0];

  float hreg[NSS][4];
  #pragma unroll
  for (int s = 0; s < NSS; ++s)
    #pragma unroll
    for (int r2 = 0; r2 < 4; ++r2) hreg[s][r2] = 0.f;

  {
    bf16x8 BA[3][4];
    #pragma unroll
    for (int tl = 0; tl < 3; ++tl) {
      const int row = (tl * 8 + wv) * 16 + c;
      #pragma unroll
      for (int k = 0; k < 4; ++k)
        BA[tl][k] = *(const bf16x8*)(whhw_b + row * HH + k * 32 + qd * 8);
    }
    #pragma unroll 2
    for (int t = 0; t < LL; ++t) {
      #pragma unroll
      for (int s = 0; s < NSS; ++s) {
        f32x4 D[3];
        #pragma unroll
        for (int tl = 0; tl < 3; ++tl) D[tl] = (f32x4){0.f, 0.f, 0.f, 0.f};
        if (t > 0) {
          const u16* hbc = hb + s * HB_SSTR + (t & 1) * HBBUF;
          bf16x8 a[4];
          #pragma unroll
          for (int k = 0; k < 4; ++k)
            a[k] = *(const bf16x8*)(hbc + c * HB_STR + (((4 * k + qd) ^ c) << 3));
          #pragma unroll
          for (int tl = 0; tl < 3; ++tl) {
            f32x4 d = D[tl];
            #pragma unroll
            for (int k = 0; k < 4; ++k)
              d = __builtin_amdgcn_mfma_f32_16x16x32_bf16(a[k], BA[tl][k], d, 0, 0, 0);
            D[tl] = d;
          }
        }
        u16* hbn = hb + s * HB_SSTR + ((t + 1) & 1) * HBBUF;
        u16* xbs = xb + s * XB_SSTR;
        #pragma unroll
        for (int reg = 0; reg < 4; ++reg) {
          const int ml = qd * 4 + reg;
          const int u = suf[(s * 16 + ml) * LL + t];
          const float r = sig2_(bf2f(WLb[i0 * LL + u]) + D[0][reg] + bw1);
          const float z = sig2_(bf2f(WLb[(HH + i0) * LL + u]) + D[1][reg] + bw2);
          const float n = tanh2_(bf2f(WLb[(2 * HH + i0) * LL + u]) + bw3
                                 + r * (D[2][reg] + bw4));
          const float hn = n + z * (hreg[s][reg] - n);
          hreg[s][reg] = hn;
          const u16 hv = f2bf(hn);
          const int slot = (((i0 >> 3) ^ ml) << 3) + (i0 & 7);
          hbn[ml * HB_STR + slot] = hv;
          xbs[(t * 16 + ml) * XB_STR + slot] = hv;
        }
      }
      __syncthreads();
    }
  }

  const bool anyf = (*sany != 0);

  if (anyf) {
    if (tid < ORIGF) ((float*)(sm + BWHN_OFF))[tid] = b_ss[tid];
    for (int idx = tid; idx < HH * ORIGF; idx += TA) {
      const int kc = idx & 127, o = idx >> 7;
      float* dst = (kc < WSSA_ROWS)
          ? (float*)(sm + WSSA_OFF + kc * 256)
          : (float*)(sm + WSSB_OFF + (kc - WSSA_ROWS) * 256);
      dst[o] = W_ss[o * HH + kc];
    }
  }

  bf16x8 BW[3][8], BC[3][4];
  #pragma unroll
  for (int tl = 0; tl < 3; ++tl) {
    const int row = (tl * 8 + wv) * 16 + c;
    #pragma unroll
    for (int kk = 0; kk < 8; ++kk)
      BW[tl][kk] = *(const bf16x8*)(wih_b + row * 256 + kk * 32 + qd * 8);
    #pragma unroll
    for (int k = 0; k < 4; ++k)
      BC[tl][k] = *(const bf16x8*)(whh_b + row * HH + k * 32 + qd * 8);
  }

  float pAcc = 0.f, pBcc = 0.f, pScc = 0.f;

  #pragma unroll 2
  for (int t = 0; t < LL; ++t) {
    #pragma unroll
    for (int s = 0; s < NSS; ++s) {
      const int node = swf[(s * 16 + c) * LL + t];
      bf16x8 ah[4];
      if constexpr (BF) {
        const u16* hp = hf16 + (size_t)node * HH + qd * 8;
        #pragma unroll
        for (int k = 0; k < 4; ++k) ah[k] = *(const bf16x8*)(hp + k * 32);
      } else {
        const float* hp = hfeat + (size_t)node * HH + qd * 8;
        #pragma unroll
        for (int k = 0; k < 4; ++k)
          ah[k] = pack8(*(const float4*)(hp + k * 32),
                        *(const float4*)(hp + k * 32 + 4));
      }
      const u16* xbs = xb + s * XB_SSTR + t * 16 * XB_STR;
      bf16x8 ay[4];
      #pragma unroll
      for (int k = 0; k < 4; ++k)
        ay[k] = *(const bf16x8*)(xbs + c * XB_STR + (((4 * k + qd) ^ c) << 3));
      const u16* hbc = hb + s * HB_SSTR + (t & 1) * HBBUF;
      bf16x8 a[4];
      #pragma unroll
      for (int k = 0; k < 4; ++k)
        a[k] = *(const bf16x8*)(hbc + c * HB_STR + (((4 * k + qd) ^ c) << 3));

      f32x4 Drz[2], Dnr, Dni;
      #pragma unroll
      for (int tl = 0; tl < 2; ++tl) {
        f32x4 d = {0.f, 0.f, 0.f, 0.f};
        #pragma unroll
        for (int k = 0; k < 4; ++k)
          d = __builtin_amdgcn_mfma_f32_16x16x32_bf16(a[k], BC[tl][k], d, 0, 0, 0);
        #pragma unroll
        for (int k = 0; k < 4; ++k)
          d = __builtin_amdgcn_mfma_f32_16x16x32_bf16(ah[k], BW[tl][k], d, 0, 0, 0);
        #pragma unroll
        for (int k = 0; k < 4; ++k)
          d = __builtin_amdgcn_mfma_f32_16x16x32_bf16(ay[k], BW[tl][4 + k], d, 0, 0, 0);
        Drz[tl] = d;
      }
      {
        f32x4 dr = {0.f, 0.f, 0.f, 0.f}, di = {0.f, 0.f, 0.f, 0.f};
        #pragma unroll
        for (int k = 0; k < 4; ++k)
          dr = __builtin_amdgcn_mfma_f32_16x16x32_bf16(a[k], BC[2][k], dr, 0, 0, 0);
        #pragma unroll
        for (int k = 0; k < 4; ++k)
          di = __builtin_amdgcn_mfma_f32_16x16x32_bf16(ah[k], BW[2][k], di, 0, 0, 0);
        #pragma unroll
        for (int k = 0; k < 4; ++k)
          di = __builtin_amdgcn_mfma_f32_16x16x32_bf16(ay[k], BW[2][4 + k], di, 0, 0, 0);
        Dnr = dr; Dni = di;
      }
      u16* hbn = hb + s * HB_SSTR + ((t + 1) & 1) * HBBUF;
      #pragma unroll
      for (int reg = 0; reg < 4; ++reg) {
        const int ml = qd * 4 + reg;
        const float r = sig2_(Drz[0][reg] + bm1);
        const float z = sig2_(Drz[1][reg] + bm2);
        const float n = tanh2_(Dni[reg] + bm3 + r * (Dnr[reg] + bm4));
        const float hn = n + z * (hreg[s][reg] - n);
        hreg[s][reg] = hn;
        hbn[ml * HB_STR + (((i0 >> 3) ^ ml) << 3) + (i0 & 7)] = f2bf(hn);
      }
    }

    if (t < LL - 1 && anyf) {
      __syncthreads();
      const float* bssl = (const float*)(sm + BWHN_OFF);
      for (int idx = tid; idx < MAS * ORIGF; idx += TA) {
        const int m = idx >> 6, o = idx & 63;
        const int cnt = scnt[m];
        if (cnt > 0) {
          const int ml = m & 15;
          const u16* hrow = hb + (m >> 4) * HB_SSTR + ((t + 1) & 1) * HBBUF
                          + ml * HB_STR;
          const float fc = (float)cnt;
          const float yt = y0[(size_t)swf[m * LL + t + 1] * ORIGF + o];
          float a0 = bssl[o], a1 = 0.f, a2 = 0.f, a3 = 0.f;
          #pragma unroll 1
          for (int kc8 = 0; kc8 < 16; ++kc8) {
            const bf16x8 xv = *(const bf16x8*)(hrow + ((kc8 ^ ml) << 3));
            const int kc = kc8 * 8;
            const char* wbase = (kc < WSSA_ROWS)
                ? (sm + WSSA_OFF + kc * 256)
                : (sm + WSSB_OFF + (kc - WSSA_ROWS) * 256);
            a0 = fmaf(((const float*)(wbase))[o],        bf2f((u16)xv[0]), a0);
            a1 = fmaf(((const float*)(wbase + 256))[o],  bf2f((u16)xv[1]), a1);
            a2 = fmaf(((const float*)(wbase + 512))[o],  bf2f((u16)xv[2]), a2);
            a3 = fmaf(((const float*)(wbase + 768))[o],  bf2f((u16)xv[3]), a3);
            a0 = fmaf(((const float*)(wbase + 1024))[o], bf2f((u16)xv[4]), a0);
            a1 = fmaf(((const float*)(wbase + 1280))[o], bf2f((u16)xv[5]), a1);
            a2 = fmaf(((const float*)(wbase + 1536))[o], bf2f((u16)xv[6]), a2);
            a3 = fmaf(((const float*)(wbase + 1792))[o], bf2f((u16)xv[7]), a3);
          }
          const float acc = (a0 + a1) + (a2 + a3);
          const float sp = softplusf_(-acc);
          pAcc += fc * yt * sp;
          pBcc += fc * (1.f - yt) * (sp + acc);
          pScc += fc * yt;
        }
      }
    }
    __syncthreads();
  }

  #pragma unroll
  for (int s = 0; s < NSS; ++s)
    #pragma unroll
    for (int reg = 0; reg < 4; ++reg)
      out[(size_t)(q0 + s * 16 + qd * 4 + reg) * HH + i0] = hreg[s][reg];

  if (anyf) {
    float* red = (float*)(sm + RED_OFF);
    red[tid] = pAcc; red[TA + tid] = pBcc; red[2 * TA + tid] = pScc;
    __syncthreads();
    if (wv == 0) {
      float a = 0.f, b = 0.f, s = 0.f;
      for (int k2 = lane; k2 < TA; k2 += 64) {
        a += red[k2]; b += red[TA + k2]; s += red[2 * TA + k2];
      }
      #pragma unroll
      for (int off = 32; off > 0; off >>= 1) {
        a += __shfl_down(a, off); b += __shfl_down(b, off); s += __shfl_down(s, off);
      }
      if (lane == 0) {
        atomicAdd(&ws[1], a); atomicAdd(&ws[2], b); atomicAdd(&ws[3], s);
      }
    }
  }
}

template<bool BF>
__global__ __launch_bounds__(TA, 2) void k_rum(
    const float* __restrict__ hfeat, const float* __restrict__ y0,
    const float* __restrict__ WihW,  const float* __restrict__ bihW,
    const float* __restrict__ bhhW,
    const float* __restrict__ bih,   const float* __restrict__ bhh,
    const float* __restrict__ W_ss,  const float* __restrict__ b_ss,
    const int* __restrict__ walks,   const int* __restrict__ idxs,
    float* __restrict__ out, float* __restrict__ ws)
{
  const int b = blockIdx.x;
  if (b < FATB) {
    rum_body<BF, 3>(b * 48, hfeat, y0, WihW, bihW, bhhW, bih, bhh,
                    W_ss, b_ss, walks, idxs, out, ws);
  } else {
    rum_body<BF, 1>(FATQ + (b - FATB) * 16, hfeat, y0, WihW, bihW, bhhW,
                    bih, bhh, W_ss, b_ss, walks, idxs, out, ws);
  }
}

__global__ void k_final(const float* __restrict__ ws, float* __restrict__ out) {
  if (threadIdx.x == 0) {
    const float cnt = (float)(SSS * SUBN * (LL - 1) * ORIGF);  // 179200
    const float pos_w = cnt / ws[3];
    const float loss = (pos_w * ws[1] + ws[2]) / cnt;
    out[NSEQ * HH] = loss;
  }
}

extern "C" void kernel_launch(void* const* d_in, const int* in_sizes, int n_in,
                              void* d_out, int out_size, void* d_ws, size_t ws_size,
                              hipStream_t stream) {
  const float* hfeat = (const float*)d_in[0];
  const float* y0    = (const float*)d_in[1];
  const float* Wih_w = (const float*)d_in[2];
  const float* Whh_w = (const float*)d_in[3];
  const float* bih_w = (const float*)d_in[4];
  const float* bhh_w = (const float*)d_in[5];
  const float* Wih   = (const float*)d_in[6];
  const float* Whh   = (const float*)d_in[7];
  const float* bih   = (const float*)d_in[8];
  const float* bhh   = (const float*)d_in[9];
  const float* W_ss  = (const float*)d_in[10];
  const float* b_ss  = (const float*)d_in[11];
  const int* walks = (const int*)d_in[12];
  const int* idxs  = (const int*)d_in[13];
  float* out = (float*)d_out;
  float* ws = (float*)d_ws;

  const bool bf  = (ws_size >= WS_NEED);     // constant across calls
  const bool big = (ws_size >= WS_NEED2);    // y_walk fits in ws

  (void)hipFuncSetAttribute((const void*)k_rum5,
                            hipFuncAttributeMaxDynamicSharedMemorySize, Q_LDS);
  (void)hipFuncSetAttribute((const void*)k_rum<true>,
                            hipFuncAttributeMaxDynamicSharedMemorySize, LDS_TOTAL);
  (void)hipFuncSetAttribute((const void*)k_rum<false>,
                            hipFuncAttributeMaxDynamicSharedMemorySize, LDS_TOTAL);

  k_zero<<<1, 64, 0, stream>>>(ws);
  k_prep<<<W_TOTAL / 256, 256, 0, stream>>>(Whh_w, Whh, Wih, ws);
  if (bf) k_prep_h<<<(NN * HH) / 256, 256, 0, stream>>>(hfeat, ws);

  if (bf && big) {
    k_rum5<<<GRID5, TA, Q_LDS, stream>>>(y0, Wih_w, bih_w, bhh_w,
                                         bih, bhh, W_ss, b_ss,
                                         walks, idxs, out, ws);
  } else if (bf) {
    k_rum<true><<<GRID, TA, LDS_TOTAL, stream>>>(hfeat, y0, Wih_w, bih_w, bhh_w,
                                                 bih, bhh, W_ss, b_ss,
                                                 walks, idxs, out, ws);
  } else {
    k_rum<false><<<GRID, TA, LDS_TOTAL, stream>>>(hfeat, y0, Wih_w, bih_w, bhh_w,
                                                  bih, bhh, W_ss, b_ss,
                                                  walks, idxs, out, ws);
  }

  k_final<<<1, 64, 0, stream>>>(ws, out);
}

// Round 13
// 357.801 us; speedup vs baseline: 1.1308x; 1.1308x over previous
//
#include <hip/hip_runtime.h>
#include <math.h>

#define NN    10000
#define SSS   4
#define LL    8
#define HH    128
#define NSEQ  40000
#define SUBN  100
#define ORIGF 64
#define TA    512

// heterogeneous tiling: 768 fat blocks (48 seqs, 3 streams) = exactly 3 rounds
// on 256 CUs, then 196 thin blocks (16 seqs, 1 stream) as a short tail round.
#define FATB  768
#define FATQ  (FATB * 48)
#define TAILB ((NSEQ - FATQ) / 16)
#define GRID  (FATB + TAILB)

typedef unsigned short u16;
typedef short bf16x8 __attribute__((ext_vector_type(8)));
typedef float f32x4 __attribute__((ext_vector_type(4)));

#define L2E 1.4426950408889634f

// ---- LDS layout (bytes), sized for NSS=3 (max) ----
// HB/XB rows are 128 u16 (256 B = 16 segs of 16 B), XOR-swizzled:
//   stored[row][seg] = data[row][seg ^ (row & 15)]
#define WL_OFF    0        // u16[3072]; dead after walk -> W_ss^T rows 0..23
#define BWRZ_OFF  6144
#define BWIN_OFF  7168
#define BWHN_OFF  7680     // f32[128]; dead after bias regs -> b_ss f32[64]
#define BMRZ_OFF  8192
#define BMIN_OFF  9216
#define BMHN_OFF  9728
#define HB_OFF    10240    // u16[NSS][2 dbuf][16*128] bf16 h (also SS snapshot)
#define HB_STR    128
#define HBBUF     2048
#define HB_SSTR   4096
#define XB_OFF    34816    // u16[NSS][128*128] y_walk rows (t*16+ml)
#define XB_STR    128
#define XB_SSTR   16384
#define SWF_OFF   133120   // int[48*8]
#define SUF_OFF   134656   // int[48*8]; dead after walk -> actm[] list
#define SCNT_OFF  136192   // int[48]
#define SANY_OFF  136384   // int sany; int nact at +4
#define WSSA_ROWS 24
#define WSSA_OFF  WL_OFF
#define WSSB_OFF  136448
#define RED_OFF   136448
#define LDS_TOTAL 163072

// ws: ws[0..3] accum; byte 64: bf16 weights (whhw|whh|wih) then bf16 hfeat
#define WB_BYTE_OFF 64
#define W_HHW_N 49152
#define W_HH_N  49152
#define W_IH_N  98304
#define W_TOTAL (W_HHW_N + W_HH_N + W_IH_N)
#define WS_NEED ((size_t)WB_BYTE_OFF + (size_t)W_TOTAL * 2 + (size_t)NN * HH * 2)

__device__ __forceinline__ float bf2f(u16 u) {
  return __uint_as_float(((unsigned)u) << 16);
}
__device__ __forceinline__ u16 f2bf(float f) {
  unsigned u = __float_as_uint(f);
  u += 0x7fffu + ((u >> 16) & 1u);   // RNE
  return (u16)(u >> 16);
}
__device__ __forceinline__ bf16x8 pack8(float4 v0, float4 v1) {
  bf16x8 r;
  r[0] = (short)f2bf(v0.x); r[1] = (short)f2bf(v0.y);
  r[2] = (short)f2bf(v0.z); r[3] = (short)f2bf(v0.w);
  r[4] = (short)f2bf(v1.x); r[5] = (short)f2bf(v1.y);
  r[6] = (short)f2bf(v1.z); r[7] = (short)f2bf(v1.w);
  return r;
}
// Gate math in exp2 domain (weights/biases prescaled by L2E / 2*L2E).
__device__ __forceinline__ float sig2_(float xs) {
  return __builtin_amdgcn_rcpf(1.f + __builtin_amdgcn_exp2f(-xs));
}
__device__ __forceinline__ float tanh2_(float xs) {   // NaN-free
  return 1.f - 2.f * __builtin_amdgcn_rcpf(__builtin_amdgcn_exp2f(xs) + 1.f);
}
__device__ __forceinline__ float softplusf_(float x) {
  return fmaxf(x, 0.f) + log1pf(__expf(-fabsf(x)));
}

__global__ void k_zero(float* ws) {
  if (threadIdx.x < 4) ws[threadIdx.x] = 0.f;
}

// Prescale GRU weights by L2E (r,z rows) / 2*L2E (n rows) while casting to bf16.
__global__ void k_prep(const float* __restrict__ whhw, const float* __restrict__ whh,
                       const float* __restrict__ wih, float* __restrict__ ws) {
  const int i = blockIdx.x * 256 + threadIdx.x;
  u16* wb = (u16*)((char*)ws + WB_BYTE_OFF);
  if (i < W_HHW_N) {
    const int row = i >> 7;
    wb[i] = f2bf(whhw[i] * ((row < 256) ? L2E : 2.f * L2E));
  } else if (i < W_HHW_N + W_HH_N) {
    const int j = i - W_HHW_N, row = j >> 7;
    wb[i] = f2bf(whh[j] * ((row < 256) ? L2E : 2.f * L2E));
  } else {
    const int j = i - W_HHW_N - W_HH_N, row = j >> 8;
    wb[i] = f2bf(wih[j] * ((row < 256) ? L2E : 2.f * L2E));
  }
}

__global__ void k_prep_h(const float* __restrict__ h, float* __restrict__ ws) {
  const int i = blockIdx.x * 256 + threadIdx.x;
  u16* hb16 = (u16*)((char*)ws + WB_BYTE_OFF) + W_TOTAL;
  hb16[i] = f2bf(h[i]);
}

// NSS = streams of 16 sequences handled by this block (compile-time).
// Hard-won constraints (R1/R6/R7/R9/R11):
//  - NO persistent prefetch state across SS/barriers (spills at 128-VGPR cap)
//  - SS inner loop stays `#pragma unroll 1` (full unroll -> spills)
//  - y_walk (XB) stays in LDS (global XB costs +1.2k cy/stream-step, R11)
template<bool BF, int NSS>
__device__ __forceinline__ void rum_body(
    const int q0,
    const float* __restrict__ hfeat, const float* __restrict__ y0,
    const float* __restrict__ WihW,  const float* __restrict__ bihW,
    const float* __restrict__ bhhW,
    const float* __restrict__ bih,   const float* __restrict__ bhh,
    const float* __restrict__ W_ss,  const float* __restrict__ b_ss,
    const int* __restrict__ walks,   const int* __restrict__ idxs,
    float* __restrict__ out, float* __restrict__ ws)
{
  constexpr int MAS = 16 * NSS;
  extern __shared__ char sm[];
  u16*   WLb  = (u16*)(sm + WL_OFF);
  float* bwrz = (float*)(sm + BWRZ_OFF);
  float* bwin = (float*)(sm + BWIN_OFF);
  float* bwhn = (float*)(sm + BWHN_OFF);
  float* bmrz = (float*)(sm + BMRZ_OFF);
  float* bmin = (float*)(sm + BMIN_OFF);
  float* bmhn = (float*)(sm + BMHN_OFF);
  u16*   hb   = (u16*)(sm + HB_OFF);
  u16*   xb   = (u16*)(sm + XB_OFF);
  int*   swf  = (int*)(sm + SWF_OFF);
  int*   suf  = (int*)(sm + SUF_OFF);
  int*   scnt = (int*)(sm + SCNT_OFF);
  int*   sany = (int*)(sm + SANY_OFF);
  int*   nact = sany + 1;
  int*   actm = (int*)(sm + SUF_OFF);   // suf dead after walk phase

  const u16* wb     = (const u16*)((const char*)ws + WB_BYTE_OFF);
  const u16* whhw_b = wb;
  const u16* whh_b  = wb + W_HHW_N;
  const u16* wih_b  = wb + W_HHW_N + W_HH_N;
  const u16* hf16   = wb + W_TOTAL;

  const int tid = threadIdx.x;
  const int lane = tid & 63, c = lane & 15, qd = lane >> 4;
  const int wv = tid >> 6;
  const int i0 = wv * 16 + c;

  // ---- phase 0 (tiling is exact: no q-bounds guards needed) ----
  if (tid < MAS) {
    const int m = tid;
    scnt[m] = 0;
    const int q = q0 + m;
    int w[LL];
    #pragma unroll
    for (int l = 0; l < LL; ++l) w[l] = walks[q * LL + l];
    #pragma unroll
    for (int l = 0; l < LL; ++l) {
      int u = l;
      #pragma unroll
      for (int l2 = LL - 1; l2 >= 0; --l2) if (w[l2] == w[l]) u = l2;
      swf[m * LL + (LL - 1 - l)] = w[l];
      suf[m * LL + (LL - 1 - l)] = u;
    }
  }
  if (tid == 0) { *sany = 0; *nact = 0; }
  for (int idx = tid; idx < 3072; idx += TA)
    WLb[idx] = f2bf(WihW[idx] * ((idx < 2048) ? L2E : 2.f * L2E));
  if (tid < 256) {
    bwrz[tid] = (bihW[tid] + bhhW[tid]) * L2E;
    bmrz[tid] = (bih[tid] + bhh[tid]) * L2E;
  }
  if (tid < 128) {
    bwin[tid] = 2.f * L2E * bihW[256 + tid]; bwhn[tid] = 2.f * L2E * bhhW[256 + tid];
    bmin[tid] = 2.f * L2E * bih[256 + tid];  bmhn[tid] = 2.f * L2E * bhh[256 + tid];
  }
  __syncthreads();

  for (int p = tid; p < MAS * SUBN; p += TA) {
    const int m = p / SUBN, i = p % SUBN;
    if (idxs[i] == (q0 + m) % NN) { atomicAdd(&scnt[m], 1); *sany = 1; }
  }

  const float bw1 = bwrz[i0], bw2 = bwrz[HH + i0], bw3 = bwin[i0], bw4 = bwhn[i0];
  const float bm1 = bmrz[i0], bm2 = bmrz[HH + i0], bm3 = bmin[i0], bm4 = bmhn[i0];

  float hreg[NSS][4];
  #pragma unroll
  for (int s = 0; s < NSS; ++s)
    #pragma unroll
    for (int r2 = 0; r2 < 4; ++r2) hreg[s][r2] = 0.f;

  // ---- walk GRU: NSS streams, 1 barrier/step ----
  {
    bf16x8 BA[3][4];
    #pragma unroll
    for (int tl = 0; tl < 3; ++tl) {
      const int row = (tl * 8 + wv) * 16 + c;
      #pragma unroll
      for (int k = 0; k < 4; ++k)
        BA[tl][k] = *(const bf16x8*)(whhw_b + row * HH + k * 32 + qd * 8);
    }
    #pragma unroll 2
    for (int t = 0; t < LL; ++t) {
      #pragma unroll
      for (int s = 0; s < NSS; ++s) {
        f32x4 D[3];
        #pragma unroll
        for (int tl = 0; tl < 3; ++tl) D[tl] = (f32x4){0.f, 0.f, 0.f, 0.f};
        if (t > 0) {
          const u16* hbc = hb + s * HB_SSTR + (t & 1) * HBBUF;
          bf16x8 a[4];
          #pragma unroll
          for (int k = 0; k < 4; ++k)
            a[k] = *(const bf16x8*)(hbc + c * HB_STR + (((4 * k + qd) ^ c) << 3));
          #pragma unroll
          for (int tl = 0; tl < 3; ++tl) {
            f32x4 d = D[tl];
            #pragma unroll
            for (int k = 0; k < 4; ++k)
              d = __builtin_amdgcn_mfma_f32_16x16x32_bf16(a[k], BA[tl][k], d, 0, 0, 0);
            D[tl] = d;
          }
        }
        u16* hbn = hb + s * HB_SSTR + ((t + 1) & 1) * HBBUF;
        u16* xbs = xb + s * XB_SSTR;
        #pragma unroll
        for (int reg = 0; reg < 4; ++reg) {
          const int ml = qd * 4 + reg;
          const int u = suf[(s * 16 + ml) * LL + t];
          const float r = sig2_(bf2f(WLb[i0 * LL + u]) + D[0][reg] + bw1);
          const float z = sig2_(bf2f(WLb[(HH + i0) * LL + u]) + D[1][reg] + bw2);
          const float n = tanh2_(bf2f(WLb[(2 * HH + i0) * LL + u]) + bw3
                                 + r * (D[2][reg] + bw4));
          const float hn = n + z * (hreg[s][reg] - n);
          hreg[s][reg] = hn;
          const u16 hv = f2bf(hn);
          const int slot = (((i0 >> 3) ^ ml) << 3) + (i0 & 7);
          hbn[ml * HB_STR + slot] = hv;
          xbs[(t * 16 + ml) * XB_STR + slot] = hv;
        }
      }
      __syncthreads();
    }
  }

  const bool anyf = (*sany != 0);

  // ---- compact active-m list (suf dead now; nact zeroed in phase 0).
  // Visibility: reads happen after the SS-branch __syncthreads at t=0.
  if (tid < MAS && scnt[tid] > 0) {
    const int p = atomicAdd(nact, 1);
    actm[p] = tid;
  }

  // ---- stage W_ss^T (f32) + b_ss into LDS (anyf blocks only) ----
  if (anyf) {
    if (tid < ORIGF) ((float*)(sm + BWHN_OFF))[tid] = b_ss[tid];
    for (int idx = tid; idx < HH * ORIGF; idx += TA) {
      const int kc = idx & 127, o = idx >> 7;
      float* dst = (kc < WSSA_ROWS)
          ? (float*)(sm + WSSA_OFF + kc * 256)
          : (float*)(sm + WSSB_OFF + (kc - WSSA_ROWS) * 256);
      dst[o] = W_ss[o * HH + kc];
    }
  }

  // ---- load main-phase weight fragments (shared by all streams) ----
  bf16x8 BW[3][8], BC[3][4];
  #pragma unroll
  for (int tl = 0; tl < 3; ++tl) {
    const int row = (tl * 8 + wv) * 16 + c;
    #pragma unroll
    for (int kk = 0; kk < 8; ++kk)
      BW[tl][kk] = *(const bf16x8*)(wih_b + row * 256 + kk * 32 + qd * 8);
    #pragma unroll
    for (int k = 0; k < 4; ++k)
      BC[tl][k] = *(const bf16x8*)(whh_b + row * HH + k * 32 + qd * 8);
  }

  float pAcc = 0.f, pBcc = 0.f, pScc = 0.f;

  // ---- main GRU: NSS streams, in-loop direct gather (R5 style) ----
  // r,z: recurrent+input GEMMs share one accumulator. n: split (r scales only
  // the recurrent part — round-3 lesson).
  #pragma unroll 2
  for (int t = 0; t < LL; ++t) {
    #pragma unroll
    for (int s = 0; s < NSS; ++s) {
      const int node = swf[(s * 16 + c) * LL + t];
      bf16x8 ah[4];
      if constexpr (BF) {
        const u16* hp = hf16 + (size_t)node * HH + qd * 8;
        #pragma unroll
        for (int k = 0; k < 4; ++k) ah[k] = *(const bf16x8*)(hp + k * 32);
      } else {
        const float* hp = hfeat + (size_t)node * HH + qd * 8;
        #pragma unroll
        for (int k = 0; k < 4; ++k)
          ah[k] = pack8(*(const float4*)(hp + k * 32),
                        *(const float4*)(hp + k * 32 + 4));
      }
      const u16* xbs = xb + s * XB_SSTR + t * 16 * XB_STR;
      bf16x8 ay[4];
      #pragma unroll
      for (int k = 0; k < 4; ++k)
        ay[k] = *(const bf16x8*)(xbs + c * XB_STR + (((4 * k + qd) ^ c) << 3));
      const u16* hbc = hb + s * HB_SSTR + (t & 1) * HBBUF;
      bf16x8 a[4];
      #pragma unroll
      for (int k = 0; k < 4; ++k)
        a[k] = *(const bf16x8*)(hbc + c * HB_STR + (((4 * k + qd) ^ c) << 3));

      f32x4 Drz[2], Dnr, Dni;
      #pragma unroll
      for (int tl = 0; tl < 2; ++tl) {      // r,z fused
        f32x4 d = {0.f, 0.f, 0.f, 0.f};
        #pragma unroll
        for (int k = 0; k < 4; ++k)
          d = __builtin_amdgcn_mfma_f32_16x16x32_bf16(a[k], BC[tl][k], d, 0, 0, 0);
        #pragma unroll
        for (int k = 0; k < 4; ++k)
          d = __builtin_amdgcn_mfma_f32_16x16x32_bf16(ah[k], BW[tl][k], d, 0, 0, 0);
        #pragma unroll
        for (int k = 0; k < 4; ++k)
          d = __builtin_amdgcn_mfma_f32_16x16x32_bf16(ay[k], BW[tl][4 + k], d, 0, 0, 0);
        Drz[tl] = d;
      }
      {                                      // n split (r scales rec only)
        f32x4 dr = {0.f, 0.f, 0.f, 0.f}, di = {0.f, 0.f, 0.f, 0.f};
        #pragma unroll
        for (int k = 0; k < 4; ++k)
          dr = __builtin_amdgcn_mfma_f32_16x16x32_bf16(a[k], BC[2][k], dr, 0, 0, 0);
        #pragma unroll
        for (int k = 0; k < 4; ++k)
          di = __builtin_amdgcn_mfma_f32_16x16x32_bf16(ah[k], BW[2][k], di, 0, 0, 0);
        #pragma unroll
        for (int k = 0; k < 4; ++k)
          di = __builtin_amdgcn_mfma_f32_16x16x32_bf16(ay[k], BW[2][4 + k], di, 0, 0, 0);
        Dnr = dr; Dni = di;
      }
      u16* hbn = hb + s * HB_SSTR + ((t + 1) & 1) * HBBUF;
      #pragma unroll
      for (int reg = 0; reg < 4; ++reg) {
        const int ml = qd * 4 + reg;
        const float r = sig2_(Drz[0][reg] + bm1);
        const float z = sig2_(Drz[1][reg] + bm2);
        const float n = tanh2_(Dni[reg] + bm3 + r * (Dnr[reg] + bm4));
        const float hn = n + z * (hreg[s][reg] - n);
        hreg[s][reg] = hn;
        hbn[ml * HB_STR + (((i0 >> 3) ^ ml) << 3) + (i0 & 7)] = f2bf(hn);
      }
    }

    if (t < LL - 1 && anyf) {           // block-uniform branch
      __syncthreads();                  // hbn rows complete; actm/nact visible
      const float* bssl = (const float*)(sm + BWHN_OFF);
      const int na = *nact;             // typically 1-2
      for (int idx = tid; idx < na * ORIGF; idx += TA) {
        const int m = actm[idx >> 6], o = idx & 63;
        const int cnt = scnt[m];        // > 0 by construction
        {
          const int ml = m & 15;
          const u16* hrow = hb + (m >> 4) * HB_SSTR + ((t + 1) & 1) * HBBUF
                          + ml * HB_STR;
          const float fc = (float)cnt;
          const float yt = y0[(size_t)swf[m * LL + t + 1] * ORIGF + o];
          // LDS W_ss^T dot; MUST stay unroll 1 (R9: full unroll -> spills)
          float a0 = bssl[o], a1 = 0.f, a2 = 0.f, a3 = 0.f;
          #pragma unroll 1
          for (int kc8 = 0; kc8 < 16; ++kc8) {
            const bf16x8 xv = *(const bf16x8*)(hrow + ((kc8 ^ ml) << 3));
            const int kc = kc8 * 8;
            const char* wbase = (kc < WSSA_ROWS)
                ? (sm + WSSA_OFF + kc * 256)
                : (sm + WSSB_OFF + (kc - WSSA_ROWS) * 256);
            a0 = fmaf(((const float*)(wbase))[o],        bf2f((u16)xv[0]), a0);
            a1 = fmaf(((const float*)(wbase + 256))[o],  bf2f((u16)xv[1]), a1);
            a2 = fmaf(((const float*)(wbase + 512))[o],  bf2f((u16)xv[2]), a2);
            a3 = fmaf(((const float*)(wbase + 768))[o],  bf2f((u16)xv[3]), a3);
            a0 = fmaf(((const float*)(wbase + 1024))[o], bf2f((u16)xv[4]), a0);
            a1 = fmaf(((const float*)(wbase + 1280))[o], bf2f((u16)xv[5]), a1);
            a2 = fmaf(((const float*)(wbase + 1536))[o], bf2f((u16)xv[6]), a2);
            a3 = fmaf(((const float*)(wbase + 1792))[o], bf2f((u16)xv[7]), a3);
          }
          const float acc = (a0 + a1) + (a2 + a3);
          const float sp = softplusf_(-acc);   // softplus(acc) = sp + acc
          pAcc += fc * yt * sp;
          pBcc += fc * (1.f - yt) * (sp + acc);
          pScc += fc * yt;
        }
      }
    }
    __syncthreads();
  }

  // ---- epilogue: h straight from registers ----
  #pragma unroll
  for (int s = 0; s < NSS; ++s)
    #pragma unroll
    for (int reg = 0; reg < 4; ++reg)
      out[(size_t)(q0 + s * 16 + qd * 4 + reg) * HH + i0] = hreg[s][reg];

  if (anyf) {
    float* red = (float*)(sm + RED_OFF);   // W_ss^T dead after main loop
    red[tid] = pAcc; red[TA + tid] = pBcc; red[2 * TA + tid] = pScc;
    __syncthreads();
    if (wv == 0) {
      float a = 0.f, b = 0.f, s = 0.f;
      for (int k2 = lane; k2 < TA; k2 += 64) {
        a += red[k2]; b += red[TA + k2]; s += red[2 * TA + k2];
      }
      #pragma unroll
      for (int off = 32; off > 0; off >>= 1) {
        a += __shfl_down(a, off); b += __shfl_down(b, off); s += __shfl_down(s, off);
      }
      if (lane == 0) {
        atomicAdd(&ws[1], a); atomicAdd(&ws[2], b); atomicAdd(&ws[3], s);
      }
    }
  }
}

template<bool BF>
__global__ __launch_bounds__(TA, 2) void k_rum(
    const float* __restrict__ hfeat, const float* __restrict__ y0,
    const float* __restrict__ WihW,  const float* __restrict__ bihW,
    const float* __restrict__ bhhW,
    const float* __restrict__ bih,   const float* __restrict__ bhh,
    const float* __restrict__ W_ss,  const float* __restrict__ b_ss,
    const int* __restrict__ walks,   const int* __restrict__ idxs,
    float* __restrict__ out, float* __restrict__ ws)
{
  const int b = blockIdx.x;
  if (b < FATB) {
    rum_body<BF, 3>(b * 48, hfeat, y0, WihW, bihW, bhhW, bih, bhh,
                    W_ss, b_ss, walks, idxs, out, ws);
  } else {
    rum_body<BF, 1>(FATQ + (b - FATB) * 16, hfeat, y0, WihW, bihW, bhhW,
                    bih, bhh, W_ss, b_ss, walks, idxs, out, ws);
  }
}

__global__ void k_final(const float* __restrict__ ws, float* __restrict__ out) {
  if (threadIdx.x == 0) {
    const float cnt = (float)(SSS * SUBN * (LL - 1) * ORIGF);  // 179200
    const float pos_w = cnt / ws[3];
    const float loss = (pos_w * ws[1] + ws[2]) / cnt;
    out[NSEQ * HH] = loss;
  }
}

extern "C" void kernel_launch(void* const* d_in, const int* in_sizes, int n_in,
                              void* d_out, int out_size, void* d_ws, size_t ws_size,
                              hipStream_t stream) {
  const float* hfeat = (const float*)d_in[0];
  const float* y0    = (const float*)d_in[1];
  const float* Wih_w = (const float*)d_in[2];
  const float* Whh_w = (const float*)d_in[3];
  const float* bih_w = (const float*)d_in[4];
  const float* bhh_w = (const float*)d_in[5];
  const float* Wih   = (const float*)d_in[6];
  const float* Whh   = (const float*)d_in[7];
  const float* bih   = (const float*)d_in[8];
  const float* bhh   = (const float*)d_in[9];
  const float* W_ss  = (const float*)d_in[10];
  const float* b_ss  = (const float*)d_in[11];
  const int* walks = (const int*)d_in[12];
  const int* idxs  = (const int*)d_in[13];
  float* out = (float*)d_out;
  float* ws = (float*)d_ws;

  const bool bf = (ws_size >= WS_NEED);    // constant across calls

  (void)hipFuncSetAttribute((const void*)k_rum<true>,
                            hipFuncAttributeMaxDynamicSharedMemorySize, LDS_TOTAL);
  (void)hipFuncSetAttribute((const void*)k_rum<false>,
                            hipFuncAttributeMaxDynamicSharedMemorySize, LDS_TOTAL);

  k_zero<<<1, 64, 0, stream>>>(ws);
  k_prep<<<W_TOTAL / 256, 256, 0, stream>>>(Whh_w, Whh, Wih, ws);
  if (bf) k_prep_h<<<(NN * HH) / 256, 256, 0, stream>>>(hfeat, ws);

  if (bf)
    k_rum<true><<<GRID, TA, LDS_TOTAL, stream>>>(hfeat, y0, Wih_w, bih_w, bhh_w,
                                                 bih, bhh, W_ss, b_ss,
                                                 walks, idxs, out, ws);
  else
    k_rum<false><<<GRID, TA, LDS_TOTAL, stream>>>(hfeat, y0, Wih_w, bih_w, bhh_w,
                                                  bih, bhh, W_ss, b_ss,
                                                  walks, idxs, out, ws);

  k_final<<<1, 64, 0, stream>>>(ws, out);
}